// Round 1
// baseline (1050.754 us; speedup 1.0000x reference)
//
#include <hip/hip_runtime.h>

// ---------------------------------------------------------------------------
// VariLengthInputLayer: fused multi-modality QKV + 4x4 attention + FC + LN
// Strategy: bf16 MFMA (16x16x32) for all GEMMs, f32 accumulate.
//   K1: f32->bf16 convert (input + 13 weight arrays)
//   K2: 12x GEMM  q/k/v[mod] = x[:,off:off+d] @ W^T   (128x128x64 tile, m97 structure)
//   K3: attention per (b,h): 4x4 scores, softmax, ctx; writes attn output
//   K4: GEMM fc + bias + residual -> pre-LN f32 (overlays q/k workspace)
//   K5: LayerNorm(1024) -> d_out
// Workspace: ~424 MB.
// ---------------------------------------------------------------------------

typedef unsigned short u16;
typedef short short8 __attribute__((ext_vector_type(8)));
typedef float f32x4 __attribute__((ext_vector_type(4)));

#define BM 128
#define BN 128
#define BK 64

__device__ __forceinline__ u16 f2bf(float f) {
  unsigned u = __builtin_bit_cast(unsigned, f);
  u += 0x7FFFu + ((u >> 16) & 1u);   // RNE (inputs are finite/normal)
  return (u16)(u >> 16);
}
__device__ __forceinline__ float bf2f(u16 s) {
  return __builtin_bit_cast(float, ((unsigned)s) << 16);
}

__device__ __forceinline__ void gload16(const u16* g, u16* l) {
  __builtin_amdgcn_global_load_lds(
      (const __attribute__((address_space(1))) void*)g,
      (__attribute__((address_space(3))) void*)l, 16, 0, 0);
}

// --------------------------- f32 -> bf16 convert ---------------------------
__global__ __launch_bounds__(256) void convf(const float* __restrict__ s,
                                             u16* __restrict__ d, int n4) {
  int i = blockIdx.x * blockDim.x + threadIdx.x;
  int stride = gridDim.x * blockDim.x;
  for (; i < n4; i += stride) {
    float4 v = ((const float4*)s)[i];
    ushort4 o;
    o.x = f2bf(v.x); o.y = f2bf(v.y); o.z = f2bf(v.z); o.w = f2bf(v.w);
    ((ushort4*)d)[i] = o;
  }
}

// --------------------------- GEMM C = A @ B^T ------------------------------
// A: [M x K] bf16 row-major, row stride lda (elems)
// B: [N x K] bf16 row-major (K contiguous)
// MODE 0: C -> bf16, Cb[r*ldc + c]
// MODE 1: C -> f32,  Cf[r*ldc + c] = acc + bias[c] + bf16(resid[r*ldc+c])
template <int MODE>
__global__ __launch_bounds__(256, 2)
void gemm_bt(const u16* __restrict__ A, int lda,
             const u16* __restrict__ B, int K,
             u16* __restrict__ Cb, float* __restrict__ Cf, int ldc,
             const float* __restrict__ bias, const u16* __restrict__ resid) {
  __shared__ __align__(16) u16 sA[BM * BK];
  __shared__ __align__(16) u16 sB[BN * BK];

  const int tid = threadIdx.x;
  const int w = tid >> 6;
  const int lane = tid & 63;
  const int lrow = lane >> 3;   // 0..7 (row within 8-row staging chunk)
  const int lcol = lane & 7;    // 0..7 (8-elem k-slice)
  const int wm = w >> 1, wn = w & 1;      // 2x2 wave grid, 64x64 per wave
  const int lr = lane & 15, lk = lane >> 4;

  const size_t brow = (size_t)blockIdx.y * BM;
  const int bcol = blockIdx.x * BN;

  f32x4 acc[4][4];
#pragma unroll
  for (int i = 0; i < 4; ++i)
#pragma unroll
    for (int j = 0; j < 4; ++j) acc[i][j] = (f32x4){0.f, 0.f, 0.f, 0.f};

  const u16* Ab = A + brow * (size_t)lda + lcol * 8;
  const u16* Bb = B + (size_t)bcol * K + lcol * 8;

  for (int k0 = 0; k0 < K; k0 += BK) {
#pragma unroll
    for (int j = 0; j < 4; ++j) {
      int chunk = j * 4 + w;               // wave-uniform
      int row = chunk * 8 + lrow;
      gload16(Ab + (size_t)row * lda + k0, &sA[chunk * 512]);
      gload16(Bb + (size_t)row * K + k0, &sB[chunk * 512]);
    }
    __syncthreads();
#pragma unroll
    for (int ks = 0; ks < 2; ++ks) {
      short8 af[4], bf[4];
#pragma unroll
      for (int mi = 0; mi < 4; ++mi)
        af[mi] = *(const short8*)&sA[(wm * 64 + mi * 16 + lr) * BK + ks * 32 + lk * 8];
#pragma unroll
      for (int ni = 0; ni < 4; ++ni)
        bf[ni] = *(const short8*)&sB[(wn * 64 + ni * 16 + lr) * BK + ks * 32 + lk * 8];
#pragma unroll
      for (int mi = 0; mi < 4; ++mi)
#pragma unroll
        for (int ni = 0; ni < 4; ++ni)
          acc[mi][ni] = __builtin_amdgcn_mfma_f32_16x16x32_bf16(
              af[mi], bf[ni], acc[mi][ni], 0, 0, 0);
    }
    __syncthreads();
  }

  // epilogue: C/D layout col=lane&15, row=(lane>>4)*4+reg
#pragma unroll
  for (int mi = 0; mi < 4; ++mi) {
#pragma unroll
    for (int ni = 0; ni < 4; ++ni) {
      f32x4 v = acc[mi][ni];
      int c = bcol + wn * 64 + ni * 16 + lr;
      if (MODE == 0) {
#pragma unroll
        for (int j = 0; j < 4; ++j) {
          size_t r = brow + wm * 64 + mi * 16 + lk * 4 + j;
          Cb[r * (size_t)ldc + c] = f2bf(v[j]);
        }
      } else {
        float bs = bias[c];
#pragma unroll
        for (int j = 0; j < 4; ++j) {
          size_t r = brow + wm * 64 + mi * 16 + lk * 4 + j;
          size_t idx = r * (size_t)ldc + c;
          Cf[idx] = v[j] + bs + bf2f(resid[idx]);
        }
      }
    }
  }
}

// --------------------------- attention ------------------------------------
// one wave per (b, h); lane = d in [0,64)
__global__ __launch_bounds__(256) void attn_k(const u16* __restrict__ qb,
                                              const u16* __restrict__ kb,
                                              const u16* __restrict__ vb,
                                              u16* __restrict__ ctxb,
                                              float* __restrict__ attn_out) {
  int lane = threadIdx.x & 63;
  int widx = blockIdx.x * 4 + (threadIdx.x >> 6);  // (b*16 + h)
  int bidx = widx >> 4, h = widx & 15;
  size_t base = (size_t)bidx * 4096 + h * 64 + lane;

  float q[4], k[4], v[4];
#pragma unroll
  for (int m = 0; m < 4; ++m) {
    q[m] = bf2f(qb[base + m * 1024]);
    k[m] = bf2f(kb[base + m * 1024]);
    v[m] = bf2f(vb[base + m * 1024]);
  }
  float s[16];
#pragma unroll
  for (int i = 0; i < 4; ++i)
#pragma unroll
    for (int j = 0; j < 4; ++j) s[i * 4 + j] = q[i] * k[j];
#pragma unroll
  for (int off = 32; off; off >>= 1) {
#pragma unroll
    for (int t = 0; t < 16; ++t) s[t] += __shfl_xor(s[t], off);
  }
  float a[16];
#pragma unroll
  for (int i = 0; i < 4; ++i) {
    float s0 = s[i * 4 + 0] * 0.125f, s1 = s[i * 4 + 1] * 0.125f;
    float s2 = s[i * 4 + 2] * 0.125f, s3 = s[i * 4 + 3] * 0.125f;
    float m = fmaxf(fmaxf(s0, s1), fmaxf(s2, s3));
    float e0 = __expf(s0 - m), e1 = __expf(s1 - m);
    float e2 = __expf(s2 - m), e3 = __expf(s3 - m);
    float inv = 1.0f / (e0 + e1 + e2 + e3);
    a[i * 4 + 0] = e0 * inv; a[i * 4 + 1] = e1 * inv;
    a[i * 4 + 2] = e2 * inv; a[i * 4 + 3] = e3 * inv;
  }
#pragma unroll
  for (int i = 0; i < 4; ++i) {
    float c = a[i * 4 + 0] * v[0] + a[i * 4 + 1] * v[1] +
              a[i * 4 + 2] * v[2] + a[i * 4 + 3] * v[3];
    ctxb[(size_t)bidx * 4096 + i * 1024 + h * 64 + lane] = f2bf(c);
  }
  if (lane < 16) {
    float val = 0.f;
#pragma unroll
    for (int t = 0; t < 16; ++t) val = (lane == t) ? a[t] : val;
    attn_out[(size_t)widx * 16 + lane] = val;
  }
}

// --------------------------- layernorm -------------------------------------
__global__ __launch_bounds__(256) void ln_k(const float* __restrict__ pre,
                                            const float* __restrict__ g,
                                            const float* __restrict__ b,
                                            float* __restrict__ out) {
  int row = blockIdx.x;
  int tid = threadIdx.x;
  const float4 x = *(const float4*)(pre + (size_t)row * 1024 + tid * 4);
  float s = x.x + x.y + x.z + x.w;
  float s2 = x.x * x.x + x.y * x.y + x.z * x.z + x.w * x.w;
#pragma unroll
  for (int off = 32; off; off >>= 1) {
    s += __shfl_xor(s, off);
    s2 += __shfl_xor(s2, off);
  }
  __shared__ float r1[4], r2[4];
  int w = tid >> 6, lane = tid & 63;
  if (lane == 0) { r1[w] = s; r2[w] = s2; }
  __syncthreads();
  s = r1[0] + r1[1] + r1[2] + r1[3];
  s2 = r2[0] + r2[1] + r2[2] + r2[3];
  float mu = s * (1.0f / 1024.0f);
  float inv = rsqrtf(s2 * (1.0f / 1024.0f) - mu * mu + 1e-6f);
  float4 gv = *(const float4*)(g + tid * 4);
  float4 bv = *(const float4*)(b + tid * 4);
  float4 o;
  o.x = (x.x - mu) * inv * gv.x + bv.x;
  o.y = (x.y - mu) * inv * gv.y + bv.y;
  o.z = (x.z - mu) * inv * gv.z + bv.z;
  o.w = (x.w - mu) * inv * gv.w + bv.w;
  *(float4*)(out + (size_t)row * 1024 + tid * 4) = o;
}

// ---------------------------------------------------------------------------
extern "C" void kernel_launch(void* const* d_in, const int* in_sizes, int n_in,
                              void* d_out, int out_size, void* d_ws,
                              size_t ws_size, hipStream_t stream) {
  const float* x = (const float*)d_in[0];
  const float* fcb = (const float*)d_in[14];
  const float* lng = (const float*)d_in[15];
  const float* lnb = (const float*)d_in[16];

  // workspace layout (u16 elems):
  //   xb   62,914,560 | wb 24,641,536 | qb 33,554,432 | kbuf 33,554,432
  //   vbuf 33,554,432 | ctxb 33,554,432 ; pre (f32) overlays qb+kbuf
  u16* xb = (u16*)d_ws;
  u16* wb = xb + 62914560;
  u16* qb = wb + 24641536;
  u16* kbuf = qb + 33554432;
  u16* vbuf = kbuf + 33554432;
  u16* ctxb = vbuf + 33554432;
  float* pre = (float*)qb;  // 32768x1024 f32 == q+k region (dead after attn)
  float* outp = (float*)d_out;
  float* attn_out = outp + 33554432;

  // K1: convert input + weights to bf16
  {
    int n4 = 62914560 / 4;
    convf<<<dim3(n4 / 256), 256, 0, stream>>>(x, xb, n4);
  }
  static const long woff[13] = {0,        2097152,  4194304,  6291456,
                                7340032,  8388608,  9437184,  9961472,
                                10485760, 11010048, 15204352, 19398656,
                                23592960};
  static const int wsz[13] = {2097152, 2097152, 2097152, 1048576, 1048576,
                              1048576, 524288,  524288,  524288,  4194304,
                              4194304, 4194304, 1048576};
  for (int i = 0; i < 13; ++i) {
    const float* wsrc = (const float*)d_in[1 + i];
    int n4 = wsz[i] / 4;
    convf<<<dim3((n4 + 255) / 256), 256, 0, stream>>>(wsrc, wb + woff[i], n4);
  }

  // K2: QKV projections (12 GEMMs)
  static const int xoff[4] = {0, 2048, 3072, 3584};
  static const int kdim[4] = {2048, 1024, 512, 4096};
  for (int mod = 0; mod < 4; ++mod) {
    for (int wch = 0; wch < 3; ++wch) {
      u16* dst = (wch == 0 ? qb : wch == 1 ? kbuf : vbuf) + mod * 1024;
      gemm_bt<0><<<dim3(8, 64), 256, 0, stream>>>(
          xb + xoff[mod], 7680, wb + woff[mod * 3 + wch], kdim[mod], dst,
          nullptr, 4096, nullptr, nullptr);
    }
  }

  // K3: attention (writes ctx bf16 + attn f32 output)
  attn_k<<<dim3(32768), 256, 0, stream>>>(qb, kbuf, vbuf, ctxb, attn_out);

  // K4: FC + bias + residual -> pre-LN f32
  gemm_bt<1><<<dim3(8, 256), 256, 0, stream>>>(ctxb, 1024, wb + 23592960, 1024,
                                               nullptr, pre, 1024, fcb, vbuf);

  // K5: LayerNorm -> out
  ln_k<<<dim3(32768), 256, 0, stream>>>(pre, lng, lnb, outp);
}

// Round 2
// 829.867 us; speedup vs baseline: 1.2662x; 1.2662x over previous
//
#include <hip/hip_runtime.h>

// ---------------------------------------------------------------------------
// VariLengthInputLayer: fused multi-modality QKV + 4x4 attention + FC + LN
//   K1: merged f32->bf16 convert (input + 13 weights, one dispatch)
//   K2: 4x merged GEMM  [q|k|v][mod] = x[:,off:off+d] @ Wqkv^T  (N=3072)
//   K3: attention: 4 (b,h) pairs per wave, 16-lane groups, d-split by 4
//   K4: GEMM fc + bias + residual -> pre-LN f32
//   K5: LayerNorm(1024) -> d_out
// ws (u16 elems): xb 62,914,560 | wb 24,641,536 | qkv 100,663,296 | ctxb 33,554,432
// pre (f32 32768x1024 = 134MB) overlays xb+wb head (fc_w at byte 173M is safe).
// ---------------------------------------------------------------------------

typedef unsigned short u16;
typedef short short8 __attribute__((ext_vector_type(8)));
typedef float f32x4 __attribute__((ext_vector_type(4)));

#define BM 128
#define BN 128
#define BK 64

__device__ __forceinline__ u16 f2bf(float f) {
  unsigned u = __builtin_bit_cast(unsigned, f);
  u += 0x7FFFu + ((u >> 16) & 1u);  // RNE
  return (u16)(u >> 16);
}
__device__ __forceinline__ float bf2f(u16 s) {
  return __builtin_bit_cast(float, ((unsigned)s) << 16);
}

__device__ __forceinline__ void gload16(const u16* g, u16* l) {
  __builtin_amdgcn_global_load_lds(
      (const __attribute__((address_space(1))) void*)g,
      (__attribute__((address_space(3))) void*)l, 16, 0, 0);
}

// --------------------------- merged f32 -> bf16 convert --------------------
struct CArgs {
  const float* src[14];
  unsigned long dst[14];  // u16-elem offset into ws base
  int blk0[14];           // first block of segment
  int n4[14];             // float4 count
};

__global__ __launch_bounds__(256) void convall(CArgs a, u16* __restrict__ wsb) {
  int blk = blockIdx.x;
  int s = 0;
#pragma unroll
  for (int i = 1; i < 14; ++i) s = (blk >= a.blk0[i]) ? i : s;
  int li = (blk - a.blk0[s]) * 256 + threadIdx.x;
  if (li < a.n4[s]) {
    float4 v = ((const float4*)a.src[s])[li];
    ushort4 o;
    o.x = f2bf(v.x); o.y = f2bf(v.y); o.z = f2bf(v.z); o.w = f2bf(v.w);
    ((ushort4*)(wsb + a.dst[s]))[li] = o;
  }
}

// --------------------------- GEMM C = A @ B^T ------------------------------
// A: [M x K] bf16 row-major (lda), B: [N x K] bf16 row-major (K contiguous)
// MODE 0: Cb[r*ldc + c] = bf16(acc)
// MODE 1: Cf[r*ldc + c] = acc + bias[c] + bf16 resid (qkv-v remap by row)
template <int MODE>
__global__ __launch_bounds__(256, 2)
void gemm_bt(const u16* __restrict__ A, int lda,
             const u16* __restrict__ B, int K,
             u16* __restrict__ Cb, float* __restrict__ Cf, int ldc,
             const float* __restrict__ bias, const u16* __restrict__ resid,
             int gx) {
  __shared__ __align__(16) u16 sA[BM * BK];
  __shared__ __align__(16) u16 sB[BN * BK];

  const int tid = threadIdx.x;
  const int w = tid >> 6;
  const int lane = tid & 63;
  const int lrow = lane >> 3;
  const int lcol = lane & 7;
  const int wm = w >> 1, wn = w & 1;
  const int lr = lane & 15, lk = lane >> 4;

  // bijective XCD swizzle (gridDim.x % 8 == 0 for all our launches)
  const int cpx = gridDim.x >> 3;
  const int id = (blockIdx.x & 7) * cpx + (blockIdx.x >> 3);
  const int bx = id % gx;
  const int by = id / gx;

  const size_t brow = (size_t)by * BM;
  const int bcol = bx * BN;

  f32x4 acc[4][4];
#pragma unroll
  for (int i = 0; i < 4; ++i)
#pragma unroll
    for (int j = 0; j < 4; ++j) acc[i][j] = (f32x4){0.f, 0.f, 0.f, 0.f};

  const u16* Ab = A + brow * (size_t)lda + lcol * 8;
  const u16* Bb = B + (size_t)bcol * K + lcol * 8;

  for (int k0 = 0; k0 < K; k0 += BK) {
#pragma unroll
    for (int j = 0; j < 4; ++j) {
      int chunk = j * 4 + w;  // wave-uniform LDS dest
      int row = chunk * 8 + lrow;
      gload16(Ab + (size_t)row * lda + k0, &sA[chunk * 512]);
      gload16(Bb + (size_t)row * K + k0, &sB[chunk * 512]);
    }
    __syncthreads();
#pragma unroll
    for (int ks = 0; ks < 2; ++ks) {
      short8 af[4], bfr[4];
#pragma unroll
      for (int mi = 0; mi < 4; ++mi)
        af[mi] = *(const short8*)&sA[(wm * 64 + mi * 16 + lr) * BK + ks * 32 + lk * 8];
#pragma unroll
      for (int ni = 0; ni < 4; ++ni)
        bfr[ni] = *(const short8*)&sB[(wn * 64 + ni * 16 + lr) * BK + ks * 32 + lk * 8];
#pragma unroll
      for (int mi = 0; mi < 4; ++mi)
#pragma unroll
        for (int ni = 0; ni < 4; ++ni)
          acc[mi][ni] = __builtin_amdgcn_mfma_f32_16x16x32_bf16(
              af[mi], bfr[ni], acc[mi][ni], 0, 0, 0);
    }
    __syncthreads();
  }

  // epilogue: C/D layout col=lane&15, row=(lane>>4)*4+reg
#pragma unroll
  for (int mi = 0; mi < 4; ++mi) {
#pragma unroll
    for (int ni = 0; ni < 4; ++ni) {
      f32x4 v = acc[mi][ni];
      int c = bcol + wn * 64 + ni * 16 + lr;
      if (MODE == 0) {
#pragma unroll
        for (int j = 0; j < 4; ++j) {
          size_t r = brow + wm * 64 + mi * 16 + lk * 4 + j;
          Cb[r * (size_t)ldc + c] = f2bf(v[j]);
        }
      } else {
        float bs = bias[c];
#pragma unroll
        for (int j = 0; j < 4; ++j) {
          size_t r = brow + wm * 64 + mi * 16 + lk * 4 + j;
          // residual = v[b, mod, c] with r = b*4 + mod, qkv layout
          size_t ridx = (r >> 2) * 12288 + (r & 3) * 3072 + 2048 + c;
          Cf[r * (size_t)ldc + c] = v[j] + bs + bf2f(resid[ridx]);
        }
      }
    }
  }
}

// --------------------------- attention ------------------------------------
// 4 (b,h) pairs per wave; 16-lane group per pair; lane owns d = (l&15)*4..+3
// qkv layout: [b][mod][3072] with q at +0, k at +1024, v at +2048, inner h*64+d
__global__ __launch_bounds__(256) void attn_k(const u16* __restrict__ qkv,
                                              u16* __restrict__ ctxb,
                                              float* __restrict__ attn_out) {
  const int tid = threadIdx.x;
  const int l = tid & 63;
  const int wg = blockIdx.x * 4 + (tid >> 6);  // 0..32767
  const int b = wg >> 2;
  const int h0 = (wg & 3) << 2;  // 0,4,8,12
  // lane l covers head h0 + (l>>4), d = (l&15)*4 .. +3  ->  elem ofs = l*4
  const size_t base = (size_t)b * 12288 + h0 * 64 + l * 4;

  float q[4][4], k[4][4], v[4][4];
#pragma unroll
  for (int m = 0; m < 4; ++m) {
    ushort4 uq = *(const ushort4*)(qkv + base + m * 3072);
    ushort4 uk = *(const ushort4*)(qkv + base + m * 3072 + 1024);
    ushort4 uv = *(const ushort4*)(qkv + base + m * 3072 + 2048);
    q[m][0] = bf2f(uq.x); q[m][1] = bf2f(uq.y); q[m][2] = bf2f(uq.z); q[m][3] = bf2f(uq.w);
    k[m][0] = bf2f(uk.x); k[m][1] = bf2f(uk.y); k[m][2] = bf2f(uk.z); k[m][3] = bf2f(uk.w);
    v[m][0] = bf2f(uv.x); v[m][1] = bf2f(uv.y); v[m][2] = bf2f(uv.z); v[m][3] = bf2f(uv.w);
  }

  float s[16];
#pragma unroll
  for (int i = 0; i < 4; ++i)
#pragma unroll
    for (int j = 0; j < 4; ++j) {
      float acc = q[i][0] * k[j][0];
      acc += q[i][1] * k[j][1];
      acc += q[i][2] * k[j][2];
      acc += q[i][3] * k[j][3];
      s[i * 4 + j] = acc;
    }
  // reduce within each 16-lane group
#pragma unroll
  for (int off = 1; off < 16; off <<= 1) {
#pragma unroll
    for (int t = 0; t < 16; ++t) s[t] += __shfl_xor(s[t], off);
  }

  float a[16];
#pragma unroll
  for (int i = 0; i < 4; ++i) {
    float s0 = s[i * 4 + 0] * 0.125f, s1 = s[i * 4 + 1] * 0.125f;
    float s2 = s[i * 4 + 2] * 0.125f, s3 = s[i * 4 + 3] * 0.125f;
    float m = fmaxf(fmaxf(s0, s1), fmaxf(s2, s3));
    float e0 = __expf(s0 - m), e1 = __expf(s1 - m);
    float e2 = __expf(s2 - m), e3 = __expf(s3 - m);
    float inv = 1.0f / (e0 + e1 + e2 + e3);
    a[i * 4 + 0] = e0 * inv; a[i * 4 + 1] = e1 * inv;
    a[i * 4 + 2] = e2 * inv; a[i * 4 + 3] = e3 * inv;
  }

  // ctx[b, i, h*64+d] ; row stride 1024, rows r = b*4+i
#pragma unroll
  for (int i = 0; i < 4; ++i) {
    float c0 = a[i*4+0]*v[0][0] + a[i*4+1]*v[1][0] + a[i*4+2]*v[2][0] + a[i*4+3]*v[3][0];
    float c1 = a[i*4+0]*v[0][1] + a[i*4+1]*v[1][1] + a[i*4+2]*v[2][1] + a[i*4+3]*v[3][1];
    float c2 = a[i*4+0]*v[0][2] + a[i*4+1]*v[1][2] + a[i*4+2]*v[2][2] + a[i*4+3]*v[3][2];
    float c3 = a[i*4+0]*v[0][3] + a[i*4+1]*v[1][3] + a[i*4+2]*v[2][3] + a[i*4+3]*v[3][3];
    ushort4 o;
    o.x = f2bf(c0); o.y = f2bf(c1); o.z = f2bf(c2); o.w = f2bf(c3);
    *(ushort4*)(ctxb + (size_t)b * 4096 + i * 1024 + h0 * 64 + l * 4) = o;
  }

  // attn[b, h, i, j]: wave covers 64 consecutive f32; lane picks a[l&15]
  int sel = l & 15;
  float val = a[0];
#pragma unroll
  for (int t = 1; t < 16; ++t) val = (sel == t) ? a[t] : val;
  attn_out[(size_t)b * 256 + h0 * 16 + l] = val;
}

// --------------------------- layernorm -------------------------------------
__global__ __launch_bounds__(256) void ln_k(const float* __restrict__ pre,
                                            const float* __restrict__ g,
                                            const float* __restrict__ b,
                                            float* __restrict__ out) {
  int row = blockIdx.x;
  int tid = threadIdx.x;
  const float4 x = *(const float4*)(pre + (size_t)row * 1024 + tid * 4);
  float s = x.x + x.y + x.z + x.w;
  float s2 = x.x * x.x + x.y * x.y + x.z * x.z + x.w * x.w;
#pragma unroll
  for (int off = 32; off; off >>= 1) {
    s += __shfl_xor(s, off);
    s2 += __shfl_xor(s2, off);
  }
  __shared__ float r1[4], r2[4];
  int w = tid >> 6, lane = tid & 63;
  if (lane == 0) { r1[w] = s; r2[w] = s2; }
  __syncthreads();
  s = r1[0] + r1[1] + r1[2] + r1[3];
  s2 = r2[0] + r2[1] + r2[2] + r2[3];
  float mu = s * (1.0f / 1024.0f);
  float inv = rsqrtf(s2 * (1.0f / 1024.0f) - mu * mu + 1e-6f);
  float4 gv = *(const float4*)(g + tid * 4);
  float4 bv = *(const float4*)(b + tid * 4);
  float4 o;
  o.x = (x.x - mu) * inv * gv.x + bv.x;
  o.y = (x.y - mu) * inv * gv.y + bv.y;
  o.z = (x.z - mu) * inv * gv.z + bv.z;
  o.w = (x.w - mu) * inv * gv.w + bv.w;
  *(float4*)(out + (size_t)row * 1024 + tid * 4) = o;
}

// ---------------------------------------------------------------------------
extern "C" void kernel_launch(void* const* d_in, const int* in_sizes, int n_in,
                              void* d_out, int out_size, void* d_ws,
                              size_t ws_size, hipStream_t stream) {
  const float* fcb = (const float*)d_in[14];
  const float* lng = (const float*)d_in[15];
  const float* lnb = (const float*)d_in[16];

  u16* wsb = (u16*)d_ws;
  u16* xb = wsb;                       // 62,914,560
  u16* wb = xb + 62914560;             // 24,641,536
  u16* qkv = wb + 24641536;            // 100,663,296  [b][mod][q|k|v][1024]
  u16* ctxb = qkv + 100663296;         // 33,554,432
  float* pre = (float*)d_ws;           // 134MB, overlays xb + wb head (safe: fc_w @173MB)
  float* outp = (float*)d_out;
  float* attn_out = outp + 33554432;

  // merged weight offsets within wb (u16 elems): [wq|wk|wv] per mod, then fc
  static const unsigned long woff[13] = {
      0,        2097152,  4194304,            // mod0 K=2048
      6291456,  7340032,  8388608,            // mod1 K=1024
      9437184,  9961472,  10485760,           // mod2 K=512
      11010048, 15204352, 19398656,           // mod3 K=4096
      23592960};                              // fc
  static const int wn4[13] = {524288, 524288, 524288, 262144, 262144, 262144,
                              131072, 131072, 131072, 1048576, 1048576, 1048576,
                              262144};

  // K1: one conversion dispatch for everything
  CArgs ca;
  ca.src[0] = (const float*)d_in[0];
  ca.dst[0] = 0;
  ca.n4[0] = 62914560 / 4;
  ca.blk0[0] = 0;
  int nb = ca.n4[0] / 256;
  for (int i = 0; i < 13; ++i) {
    ca.src[i + 1] = (const float*)d_in[1 + i];
    ca.dst[i + 1] = 62914560ul + woff[i];
    ca.n4[i + 1] = wn4[i];
    ca.blk0[i + 1] = nb;
    nb += (wn4[i] + 255) / 256;
  }
  convall<<<dim3(nb), 256, 0, stream>>>(ca, wsb);

  // K2: merged QKV projections (4 GEMMs, N=3072)
  static const int xoff[4] = {0, 2048, 3072, 3584};
  static const int kdim[4] = {2048, 1024, 512, 4096};
  static const unsigned long mbase[4] = {0, 6291456, 9437184, 11010048};
  for (int mod = 0; mod < 4; ++mod) {
    gemm_bt<0><<<dim3(24 * 64), 256, 0, stream>>>(
        xb + xoff[mod], 7680, wb + mbase[mod], kdim[mod], qkv + mod * 3072,
        nullptr, 12288, nullptr, nullptr, 24);
  }

  // K3: attention
  attn_k<<<dim3(8192), 256, 0, stream>>>(qkv, ctxb, attn_out);

  // K4: FC + bias + residual -> pre-LN f32
  gemm_bt<1><<<dim3(8 * 256), 256, 0, stream>>>(
      ctxb, 1024, wb + 23592960, 1024, nullptr, pre, 1024, fcb, qkv, 8);

  // K5: LayerNorm -> out
  ln_k<<<dim3(32768), 256, 0, stream>>>(pre, lng, lnb, outp);
}

// Round 3
// 666.682 us; speedup vs baseline: 1.5761x; 1.2448x over previous
//
#include <hip/hip_runtime.h>

// ---------------------------------------------------------------------------
// VariLengthInputLayer: fused multi-modality QKV + 4x4 attention + FC + LN
//   K1: merged f32->bf16 convert (one dispatch)
//   K2: grouped QKV GEMM, 256x256 tile, BK=32, 4-deep pipelined LDS, counted
//       vmcnt, per-phase setprio MFMA clusters, swizzled LDS (T1-T5 stack)
//   K3: attention: 4 (b,h) pairs per wave, 16-lane groups
//   K4: FC GEMM (same engine) + bias + residual -> pre-LN f32
//   K5: LayerNorm(1024) -> d_out
// ---------------------------------------------------------------------------

typedef unsigned short u16;
typedef short short8 __attribute__((ext_vector_type(8)));
typedef float f32x4 __attribute__((ext_vector_type(4)));

__device__ __forceinline__ u16 f2bf(float f) {
  unsigned u = __builtin_bit_cast(unsigned, f);
  u += 0x7FFFu + ((u >> 16) & 1u);  // RNE
  return (u16)(u >> 16);
}
__device__ __forceinline__ float bf2f(u16 s) {
  return __builtin_bit_cast(float, ((unsigned)s) << 16);
}

__device__ __forceinline__ void gload16(const u16* g, u16* l) {
  __builtin_amdgcn_global_load_lds(
      (const __attribute__((address_space(1))) void*)g,
      (__attribute__((address_space(3))) void*)l, 16, 0, 0);
}

#define CFENCE asm volatile("" ::: "memory")

// --------------------------- merged f32 -> bf16 convert --------------------
struct CArgs {
  const float* src[14];
  unsigned long dst[14];
  int blk0[14];
  int n4[14];
};

__global__ __launch_bounds__(256) void convall(CArgs a, u16* __restrict__ wsb) {
  int blk = blockIdx.x;
  int s = 0;
#pragma unroll
  for (int i = 1; i < 14; ++i) s = (blk >= a.blk0[i]) ? i : s;
  int li = (blk - a.blk0[s]) * 256 + threadIdx.x;
  if (li < a.n4[s]) {
    float4 v = ((const float4*)a.src[s])[li];
    ushort4 o;
    o.x = f2bf(v.x); o.y = f2bf(v.y); o.z = f2bf(v.z); o.w = f2bf(v.w);
    ((ushort4*)(wsb + a.dst[s]))[li] = o;
  }
}

// --------------------------- pipelined 256^2 GEMM --------------------------
// C = A @ B^T.  A [M x K] bf16 (row stride lda), B [N x K] bf16 (K contig).
// 512 threads = 8 waves (2M x 4N); per-wave 128x64 out; BK=32.
// LDS: 4 rotating buffers x (A[256][32] + B[256][32]) = 128 KiB, slot-swizzled
//   physical slot sp = logical_slot ^ ((row>>1)&3)   (16B slots, 64B rows)
// Pipeline: stage tile t+3 during step t (A halves in phase0, B in phase1);
//   vmcnt(8) + barrier once per K-step => tile t+1 resident. nt must be >= 3.
// MODE 0: grouped QKV (seg-> modality, LPT order), C -> qkv bf16 ldc 12288
// MODE 1: FC, C -> f32 + bias + residual(qkv v-slice), ldc 1024
template <int MODE>
__global__ __launch_bounds__(512, 1)
void gemm8(const u16* __restrict__ Abase, int lda,
           const u16* __restrict__ Wbase, u16* __restrict__ Cq,
           float* __restrict__ Cf, const float* __restrict__ bias,
           const u16* __restrict__ resid) {
  __shared__ __align__(16) u16 lds[65536];

  const int tid = threadIdx.x;
  const int w = tid >> 6, lane = tid & 63;
  const int lr = lane & 15, lk = lane >> 4;
  const int wm = w >> 2, wn = w & 3;

  int K, nt, bx, by, coff;
  const u16 *A, *B;
  if (MODE == 0) {
    int seg = blockIdx.x / 384;       // LPT: longest K first
    int r = blockIdx.x % 384;
    r = (r & 7) * 48 + (r >> 3);      // bijective XCD swizzle (384 = 8*48)
    bx = r % 12; by = r / 12;
    K = 4096 >> seg; nt = 128 >> seg;
    int xo, wo, mod;
    switch (seg) {
      case 0:  xo = 3584; wo = 11010048; mod = 3; break;
      case 1:  xo = 0;    wo = 0;        mod = 0; break;
      case 2:  xo = 2048; wo = 6291456;  mod = 1; break;
      default: xo = 3072; wo = 9437184;  mod = 2; break;
    }
    coff = mod * 3072;
    A = Abase + xo;
    B = Wbase + wo;
  } else {
    int r = (blockIdx.x & 7) * 64 + (blockIdx.x >> 3);  // 512 = 8*64
    bx = r & 3; by = r >> 2;
    K = 1024; nt = 32; coff = 0;
    A = Abase; B = Wbase;
  }
  const size_t brow = (size_t)by * 256;
  const int bcol = bx * 256;
  const u16* Ab = A + brow * (size_t)lda;
  const u16* Bb = B + (size_t)bcol * (size_t)K;

  const int stg_row = lane >> 2;                            // row within 16-row chunk
  const int stg_k = ((lane & 3) ^ ((lane >> 3) & 3)) * 8;   // pre-swizzled src k-ofs
  const int fso = (lk ^ ((lr >> 1) & 3)) * 8;               // swizzled read slot

  f32x4 acc[8][4];
#pragma unroll
  for (int i = 0; i < 8; ++i)
#pragma unroll
    for (int j = 0; j < 4; ++j) acc[i][j] = (f32x4){0.f, 0.f, 0.f, 0.f};

  auto stageA = [&](int p) {
    const int bb = (p & 3) * 16384;
    const int k0 = p * 32;
#pragma unroll
    for (int h = 0; h < 2; ++h)
      gload16(Ab + (size_t)(h * 128 + w * 16 + stg_row) * lda + k0 + stg_k,
              (u16*)&lds[bb + h * 4096 + w * 512]);
  };
  auto stageB = [&](int p) {
    const int bb = (p & 3) * 16384 + 8192;
    const int k0 = p * 32;
#pragma unroll
    for (int h = 0; h < 2; ++h)
      gload16(Bb + (size_t)(h * 128 + w * 16 + stg_row) * (size_t)K + k0 + stg_k,
              (u16*)&lds[bb + h * 4096 + w * 512]);
  };

  // prologue: stage tiles 0,1,2 (12 loads); wait tile0 (keep newest 8 in flight)
  stageA(0); stageB(0);
  stageA(1); stageB(1);
  stageA(2); stageB(2);
  asm volatile("s_waitcnt vmcnt(8)" ::: "memory");
  __builtin_amdgcn_s_barrier();
  CFENCE;

#pragma unroll 1
  for (int t = 0; t < nt; ++t) {
    const int bb = (t & 3) * 16384;
    short8 af[4], bfr[4];
    // ---- phase 0: frags A0-3 + B0-3, stage A(t+3), 16 MFMA ----
#pragma unroll
    for (int mi = 0; mi < 4; ++mi)
      af[mi] = *(const short8*)&lds[bb + (wm * 128 + mi * 16 + lr) * 32 + fso];
#pragma unroll
    for (int ni = 0; ni < 4; ++ni)
      bfr[ni] = *(const short8*)&lds[bb + 8192 + (wn * 64 + ni * 16 + lr) * 32 + fso];
    if (t + 3 < nt) stageA(t + 3);
    CFENCE;
    __builtin_amdgcn_s_barrier();
    CFENCE;
    __builtin_amdgcn_s_setprio(1);
#pragma unroll
    for (int mi = 0; mi < 4; ++mi)
#pragma unroll
      for (int ni = 0; ni < 4; ++ni)
        acc[mi][ni] = __builtin_amdgcn_mfma_f32_16x16x32_bf16(
            af[mi], bfr[ni], acc[mi][ni], 0, 0, 0);
    __builtin_amdgcn_s_setprio(0);
    CFENCE;
    __builtin_amdgcn_s_barrier();
    CFENCE;
    // ---- phase 1: frags A4-7, stage B(t+3), 16 MFMA ----
    short8 ag[4];
#pragma unroll
    for (int mi = 0; mi < 4; ++mi)
      ag[mi] = *(const short8*)&lds[bb + (wm * 128 + (mi + 4) * 16 + lr) * 32 + fso];
    if (t + 3 < nt) stageB(t + 3);
    CFENCE;
    __builtin_amdgcn_s_barrier();
    CFENCE;
    __builtin_amdgcn_s_setprio(1);
#pragma unroll
    for (int mi = 0; mi < 4; ++mi)
#pragma unroll
      for (int ni = 0; ni < 4; ++ni)
        acc[mi + 4][ni] = __builtin_amdgcn_mfma_f32_16x16x32_bf16(
            ag[mi], bfr[ni], acc[mi + 4][ni], 0, 0, 0);
    __builtin_amdgcn_s_setprio(0);
    // ---- tail: ensure tile t+1 resident; counted vmcnt, never 0 mid-loop ----
    if (t + 1 < nt) {
      if (t + 3 < nt)      asm volatile("s_waitcnt vmcnt(8)" ::: "memory");
      else if (t + 2 < nt) asm volatile("s_waitcnt vmcnt(4)" ::: "memory");
      else                 asm volatile("s_waitcnt vmcnt(0)" ::: "memory");
      __builtin_amdgcn_s_barrier();
      CFENCE;
    }
  }

  // epilogue: C/D layout col=lane&15, row=(lane>>4)*4+j
  if (MODE == 0) {
#pragma unroll
    for (int mi = 0; mi < 8; ++mi)
#pragma unroll
      for (int ni = 0; ni < 4; ++ni) {
        const int c = coff + bcol + wn * 64 + ni * 16 + lr;
#pragma unroll
        for (int j = 0; j < 4; ++j) {
          size_t r = brow + wm * 128 + mi * 16 + lk * 4 + j;
          Cq[r * 12288 + c] = f2bf(acc[mi][ni][j]);
        }
      }
  } else {
#pragma unroll
    for (int mi = 0; mi < 8; ++mi)
#pragma unroll
      for (int ni = 0; ni < 4; ++ni) {
        const int c = bcol + wn * 64 + ni * 16 + lr;
        const float bs = bias[c];
#pragma unroll
        for (int j = 0; j < 4; ++j) {
          size_t r = brow + wm * 128 + mi * 16 + lk * 4 + j;
          size_t ridx = (r >> 2) * 12288 + (r & 3) * 3072 + 2048 + c;
          Cf[r * 1024 + c] = acc[mi][ni][j] + bs + bf2f(resid[ridx]);
        }
      }
  }
}

// --------------------------- attention ------------------------------------
__global__ __launch_bounds__(256) void attn_k(const u16* __restrict__ qkv,
                                              u16* __restrict__ ctxb,
                                              float* __restrict__ attn_out) {
  const int tid = threadIdx.x;
  const int l = tid & 63;
  const int wg = blockIdx.x * 4 + (tid >> 6);
  const int b = wg >> 2;
  const int h0 = (wg & 3) << 2;
  const size_t base = (size_t)b * 12288 + h0 * 64 + l * 4;

  float q[4][4], k[4][4], v[4][4];
#pragma unroll
  for (int m = 0; m < 4; ++m) {
    ushort4 uq = *(const ushort4*)(qkv + base + m * 3072);
    ushort4 uk = *(const ushort4*)(qkv + base + m * 3072 + 1024);
    ushort4 uv = *(const ushort4*)(qkv + base + m * 3072 + 2048);
    q[m][0] = bf2f(uq.x); q[m][1] = bf2f(uq.y); q[m][2] = bf2f(uq.z); q[m][3] = bf2f(uq.w);
    k[m][0] = bf2f(uk.x); k[m][1] = bf2f(uk.y); k[m][2] = bf2f(uk.z); k[m][3] = bf2f(uk.w);
    v[m][0] = bf2f(uv.x); v[m][1] = bf2f(uv.y); v[m][2] = bf2f(uv.z); v[m][3] = bf2f(uv.w);
  }

  float s[16];
#pragma unroll
  for (int i = 0; i < 4; ++i)
#pragma unroll
    for (int j = 0; j < 4; ++j) {
      float acc = q[i][0] * k[j][0];
      acc += q[i][1] * k[j][1];
      acc += q[i][2] * k[j][2];
      acc += q[i][3] * k[j][3];
      s[i * 4 + j] = acc;
    }
#pragma unroll
  for (int off = 1; off < 16; off <<= 1) {
#pragma unroll
    for (int t = 0; t < 16; ++t) s[t] += __shfl_xor(s[t], off);
  }

  float a[16];
#pragma unroll
  for (int i = 0; i < 4; ++i) {
    float s0 = s[i * 4 + 0] * 0.125f, s1 = s[i * 4 + 1] * 0.125f;
    float s2 = s[i * 4 + 2] * 0.125f, s3 = s[i * 4 + 3] * 0.125f;
    float m = fmaxf(fmaxf(s0, s1), fmaxf(s2, s3));
    float e0 = __expf(s0 - m), e1 = __expf(s1 - m);
    float e2 = __expf(s2 - m), e3 = __expf(s3 - m);
    float inv = 1.0f / (e0 + e1 + e2 + e3);
    a[i * 4 + 0] = e0 * inv; a[i * 4 + 1] = e1 * inv;
    a[i * 4 + 2] = e2 * inv; a[i * 4 + 3] = e3 * inv;
  }

#pragma unroll
  for (int i = 0; i < 4; ++i) {
    float c0 = a[i*4+0]*v[0][0] + a[i*4+1]*v[1][0] + a[i*4+2]*v[2][0] + a[i*4+3]*v[3][0];
    float c1 = a[i*4+0]*v[0][1] + a[i*4+1]*v[1][1] + a[i*4+2]*v[2][1] + a[i*4+3]*v[3][1];
    float c2 = a[i*4+0]*v[0][2] + a[i*4+1]*v[1][2] + a[i*4+2]*v[2][2] + a[i*4+3]*v[3][2];
    float c3 = a[i*4+0]*v[0][3] + a[i*4+1]*v[1][3] + a[i*4+2]*v[2][3] + a[i*4+3]*v[3][3];
    ushort4 o;
    o.x = f2bf(c0); o.y = f2bf(c1); o.z = f2bf(c2); o.w = f2bf(c3);
    *(ushort4*)(ctxb + (size_t)b * 4096 + i * 1024 + h0 * 64 + l * 4) = o;
  }

  int sel = l & 15;
  float val = a[0];
#pragma unroll
  for (int t = 1; t < 16; ++t) val = (sel == t) ? a[t] : val;
  attn_out[(size_t)b * 256 + h0 * 16 + l] = val;
}

// --------------------------- layernorm -------------------------------------
__global__ __launch_bounds__(256) void ln_k(const float* __restrict__ pre,
                                            const float* __restrict__ g,
                                            const float* __restrict__ b,
                                            float* __restrict__ out) {
  int row = blockIdx.x;
  int tid = threadIdx.x;
  const float4 x = *(const float4*)(pre + (size_t)row * 1024 + tid * 4);
  float s = x.x + x.y + x.z + x.w;
  float s2 = x.x * x.x + x.y * x.y + x.z * x.z + x.w * x.w;
#pragma unroll
  for (int off = 32; off; off >>= 1) {
    s += __shfl_xor(s, off);
    s2 += __shfl_xor(s2, off);
  }
  __shared__ float r1[4], r2[4];
  int w = tid >> 6, lane = tid & 63;
  if (lane == 0) { r1[w] = s; r2[w] = s2; }
  __syncthreads();
  s = r1[0] + r1[1] + r1[2] + r1[3];
  s2 = r2[0] + r2[1] + r2[2] + r2[3];
  float mu = s * (1.0f / 1024.0f);
  float inv = rsqrtf(s2 * (1.0f / 1024.0f) - mu * mu + 1e-6f);
  float4 gv = *(const float4*)(g + tid * 4);
  float4 bv = *(const float4*)(b + tid * 4);
  float4 o;
  o.x = (x.x - mu) * inv * gv.x + bv.x;
  o.y = (x.y - mu) * inv * gv.y + bv.y;
  o.z = (x.z - mu) * inv * gv.z + bv.z;
  o.w = (x.w - mu) * inv * gv.w + bv.w;
  *(float4*)(out + (size_t)row * 1024 + tid * 4) = o;
}

// ---------------------------------------------------------------------------
extern "C" void kernel_launch(void* const* d_in, const int* in_sizes, int n_in,
                              void* d_out, int out_size, void* d_ws,
                              size_t ws_size, hipStream_t stream) {
  const float* fcb = (const float*)d_in[14];
  const float* lng = (const float*)d_in[15];
  const float* lnb = (const float*)d_in[16];

  u16* wsb = (u16*)d_ws;
  u16* xb = wsb;                 // 62,914,560
  u16* wb = xb + 62914560;       // 24,641,536
  u16* qkv = wb + 24641536;      // 100,663,296  [b][mod][q|k|v][1024]
  u16* ctxb = qkv + 100663296;   // 33,554,432
  float* pre = (float*)d_ws;     // 134MB overlays xb+wb head (fc_w @173MB safe)
  float* outp = (float*)d_out;
  float* attn_out = outp + 33554432;

  static const unsigned long woff[13] = {
      0,        2097152,  4194304,   // mod0 K=2048 (q,k,v)
      6291456,  7340032,  8388608,   // mod1 K=1024
      9437184,  9961472,  10485760,  // mod2 K=512
      11010048, 15204352, 19398656,  // mod3 K=4096
      23592960};                     // fc
  static const int wn4[13] = {524288, 524288, 524288, 262144, 262144, 262144,
                              131072, 131072, 131072, 1048576, 1048576, 1048576,
                              262144};

  // K1: one conversion dispatch
  CArgs ca;
  ca.src[0] = (const float*)d_in[0];
  ca.dst[0] = 0;
  ca.n4[0] = 62914560 / 4;
  ca.blk0[0] = 0;
  int nb = ca.n4[0] / 256;
  for (int i = 0; i < 13; ++i) {
    ca.src[i + 1] = (const float*)d_in[1 + i];
    ca.dst[i + 1] = 62914560ul + woff[i];
    ca.n4[i + 1] = wn4[i];
    ca.blk0[i + 1] = nb;
    nb += (wn4[i] + 255) / 256;
  }
  convall<<<dim3(nb), 256, 0, stream>>>(ca, wsb);

  // K2: grouped QKV projections, one dispatch (4 segs x 384 blocks, LPT)
  gemm8<0><<<dim3(1536), 512, 0, stream>>>(xb, 7680, wb, qkv, nullptr, nullptr,
                                           nullptr);

  // K3: attention
  attn_k<<<dim3(8192), 256, 0, stream>>>(qkv, ctxb, attn_out);

  // K4: FC + bias + residual -> pre-LN f32
  gemm8<1><<<dim3(512), 512, 0, stream>>>(ctxb, 1024, wb + 23592960, nullptr,
                                          pre, fcb, qkv);

  // K5: LayerNorm -> out
  ln_k<<<dim3(32768), 256, 0, stream>>>(pre, lng, lnb, outp);
}

// Round 4
// 659.082 us; speedup vs baseline: 1.5943x; 1.0115x over previous
//
#include <hip/hip_runtime.h>

// ---------------------------------------------------------------------------
// VariLengthInputLayer: fused multi-modality QKV + 4x4 attention + FC + LN
//   K1: merged f32->bf16 convert (one dispatch)
//   K2: grouped QKV GEMM, 256x256 tile, BK=32, 4-deep pipelined LDS, counted
//       vmcnt, ONE barrier per K-step (skewed waves overlap LDS reads w/ MFMA)
//   K3: attention: 4 (b,h) pairs per wave, 16-lane groups
//   K4: FC GEMM (same engine) + bias + residual -> pre-LN f32
//   K5: LayerNorm(1024) -> d_out
// ---------------------------------------------------------------------------

typedef unsigned short u16;
typedef short short8 __attribute__((ext_vector_type(8)));
typedef float f32x4 __attribute__((ext_vector_type(4)));

__device__ __forceinline__ u16 f2bf(float f) {
  unsigned u = __builtin_bit_cast(unsigned, f);
  u += 0x7FFFu + ((u >> 16) & 1u);  // RNE
  return (u16)(u >> 16);
}
__device__ __forceinline__ float bf2f(u16 s) {
  return __builtin_bit_cast(float, ((unsigned)s) << 16);
}

__device__ __forceinline__ void gload16(const u16* g, u16* l) {
  __builtin_amdgcn_global_load_lds(
      (const __attribute__((address_space(1))) void*)g,
      (__attribute__((address_space(3))) void*)l, 16, 0, 0);
}

#define CFENCE asm volatile("" ::: "memory")

// --------------------------- merged f32 -> bf16 convert --------------------
struct CArgs {
  const float* src[14];
  unsigned long dst[14];
  int blk0[14];
  int n4[14];
};

__global__ __launch_bounds__(256) void convall(CArgs a, u16* __restrict__ wsb) {
  int blk = blockIdx.x;
  int s = 0;
#pragma unroll
  for (int i = 1; i < 14; ++i) s = (blk >= a.blk0[i]) ? i : s;
  int li = (blk - a.blk0[s]) * 256 + threadIdx.x;
  if (li < a.n4[s]) {
    float4 v = ((const float4*)a.src[s])[li];
    ushort4 o;
    o.x = f2bf(v.x); o.y = f2bf(v.y); o.z = f2bf(v.z); o.w = f2bf(v.w);
    ((ushort4*)(wsb + a.dst[s]))[li] = o;
  }
}

// --------------------------- pipelined 256^2 GEMM --------------------------
// C = A @ B^T.  A [M x K] bf16 (row stride lda), B [N x K] bf16 (K contig).
// 512 threads = 8 waves (2M x 4N); per-wave 128x64 out; BK=32.
// LDS: 4 rotating buffers x (A[256][32] + B[256][32]) = 128 KiB, slot-swizzled
//   physical slot sp = logical_slot ^ ((row>>1)&3)   (16B slots, 64B rows)
// Pipeline: stage tile t+3 at top of step t (4 gload_lds, issued before the
//   12 frag ds_reads so HBM latency hides under 3 steps of compute);
//   ONE tail barrier per K-step after counted vmcnt (8 steady / 4 / 0 drain).
//   Waves skew freely within a step -> LDS drain overlaps MFMA across waves.
// MODE 0: grouped QKV (seg-> modality, LPT order), C -> qkv bf16 ldc 12288
// MODE 1: FC, C -> f32 + bias + residual(qkv v-slice), ldc 1024
template <int MODE>
__global__ __launch_bounds__(512, 1)
void gemm8(const u16* __restrict__ Abase, int lda,
           const u16* __restrict__ Wbase, u16* __restrict__ Cq,
           float* __restrict__ Cf, const float* __restrict__ bias,
           const u16* __restrict__ resid) {
  __shared__ __align__(16) u16 lds[65536];

  const int tid = threadIdx.x;
  const int w = tid >> 6, lane = tid & 63;
  const int lr = lane & 15, lk = lane >> 4;
  const int wm = w >> 2, wn = w & 3;

  int K, nt, bx, by, coff;
  const u16 *A, *B;
  if (MODE == 0) {
    int seg = blockIdx.x / 384;       // LPT: longest K first
    int r = blockIdx.x % 384;
    r = (r & 7) * 48 + (r >> 3);      // bijective XCD swizzle (384 = 8*48)
    bx = r % 12; by = r / 12;
    K = 4096 >> seg; nt = 128 >> seg;
    int xo, wo, mod;
    switch (seg) {
      case 0:  xo = 3584; wo = 11010048; mod = 3; break;
      case 1:  xo = 0;    wo = 0;        mod = 0; break;
      case 2:  xo = 2048; wo = 6291456;  mod = 1; break;
      default: xo = 3072; wo = 9437184;  mod = 2; break;
    }
    coff = mod * 3072;
    A = Abase + xo;
    B = Wbase + wo;
  } else {
    int r = (blockIdx.x & 7) * 64 + (blockIdx.x >> 3);  // 512 = 8*64
    bx = r & 3; by = r >> 2;
    K = 1024; nt = 32; coff = 0;
    A = Abase; B = Wbase;
  }
  const size_t brow = (size_t)by * 256;
  const int bcol = bx * 256;
  const u16* Ab = A + brow * (size_t)lda;
  const u16* Bb = B + (size_t)bcol * (size_t)K;

  const int stg_row = lane >> 2;                            // row within 16-row chunk
  const int stg_k = ((lane & 3) ^ ((lane >> 3) & 3)) * 8;   // pre-swizzled src k-ofs
  const int fso = (lk ^ ((lr >> 1) & 3)) * 8;               // swizzled read slot

  f32x4 acc[8][4];
#pragma unroll
  for (int i = 0; i < 8; ++i)
#pragma unroll
    for (int j = 0; j < 4; ++j) acc[i][j] = (f32x4){0.f, 0.f, 0.f, 0.f};

  auto stageA = [&](int p) {
    const int bb = (p & 3) * 16384;
    const int k0 = p * 32;
#pragma unroll
    for (int h = 0; h < 2; ++h)
      gload16(Ab + (size_t)(h * 128 + w * 16 + stg_row) * lda + k0 + stg_k,
              (u16*)&lds[bb + h * 4096 + w * 512]);
  };
  auto stageB = [&](int p) {
    const int bb = (p & 3) * 16384 + 8192;
    const int k0 = p * 32;
#pragma unroll
    for (int h = 0; h < 2; ++h)
      gload16(Bb + (size_t)(h * 128 + w * 16 + stg_row) * (size_t)K + k0 + stg_k,
              (u16*)&lds[bb + h * 4096 + w * 512]);
  };

  // prologue: stage tiles 0,1,2 (12 loads/wave); wait tile0 (8 newest stay)
  stageA(0); stageB(0);
  stageA(1); stageB(1);
  stageA(2); stageB(2);
  asm volatile("s_waitcnt vmcnt(8)" ::: "memory");
  __builtin_amdgcn_s_barrier();
  CFENCE;

#pragma unroll 1
  for (int t = 0; t < nt; ++t) {
    const int bb = (t & 3) * 16384;
    // issue next-tile stage first: ~3 K-steps of latency headroom
    if (t + 3 < nt) { stageA(t + 3); stageB(t + 3); }
    CFENCE;
    // frag reads; compiler interleaves fine-grained lgkmcnt with MFMAs
    short8 bfr[4], af[8];
#pragma unroll
    for (int ni = 0; ni < 4; ++ni)
      bfr[ni] = *(const short8*)&lds[bb + 8192 + (wn * 64 + ni * 16 + lr) * 32 + fso];
#pragma unroll
    for (int mi = 0; mi < 8; ++mi)
      af[mi] = *(const short8*)&lds[bb + (wm * 128 + mi * 16 + lr) * 32 + fso];
    __builtin_amdgcn_s_setprio(1);
#pragma unroll
    for (int mi = 0; mi < 8; ++mi)
#pragma unroll
      for (int ni = 0; ni < 4; ++ni)
        acc[mi][ni] = __builtin_amdgcn_mfma_f32_16x16x32_bf16(
            af[mi], bfr[ni], acc[mi][ni], 0, 0, 0);
    __builtin_amdgcn_s_setprio(0);
    CFENCE;
    // tail: ensure tile t+1 resident for everyone; never drain mid-loop
    if (t + 1 < nt) {
      if (t + 3 < nt)      asm volatile("s_waitcnt vmcnt(8)" ::: "memory");
      else if (t + 2 < nt) asm volatile("s_waitcnt vmcnt(4)" ::: "memory");
      else                 asm volatile("s_waitcnt vmcnt(0)" ::: "memory");
      __builtin_amdgcn_s_barrier();
      CFENCE;
    }
  }

  // epilogue: C/D layout col=lane&15, row=(lane>>4)*4+j
  if (MODE == 0) {
#pragma unroll
    for (int mi = 0; mi < 8; ++mi)
#pragma unroll
      for (int ni = 0; ni < 4; ++ni) {
        const int c = coff + bcol + wn * 64 + ni * 16 + lr;
#pragma unroll
        for (int j = 0; j < 4; ++j) {
          size_t r = brow + wm * 128 + mi * 16 + lk * 4 + j;
          Cq[r * 12288 + c] = f2bf(acc[mi][ni][j]);
        }
      }
  } else {
#pragma unroll
    for (int mi = 0; mi < 8; ++mi)
#pragma unroll
      for (int ni = 0; ni < 4; ++ni) {
        const int c = bcol + wn * 64 + ni * 16 + lr;
        const float bs = bias[c];
#pragma unroll
        for (int j = 0; j < 4; ++j) {
          size_t r = brow + wm * 128 + mi * 16 + lk * 4 + j;
          size_t ridx = (r >> 2) * 12288 + (r & 3) * 3072 + 2048 + c;
          Cf[r * 1024 + c] = acc[mi][ni][j] + bs + bf2f(resid[ridx]);
        }
      }
  }
}

// --------------------------- attention ------------------------------------
__global__ __launch_bounds__(256) void attn_k(const u16* __restrict__ qkv,
                                              u16* __restrict__ ctxb,
                                              float* __restrict__ attn_out) {
  const int tid = threadIdx.x;
  const int l = tid & 63;
  const int wg = blockIdx.x * 4 + (tid >> 6);
  const int b = wg >> 2;
  const int h0 = (wg & 3) << 2;
  const size_t base = (size_t)b * 12288 + h0 * 64 + l * 4;

  float q[4][4], k[4][4], v[4][4];
#pragma unroll
  for (int m = 0; m < 4; ++m) {
    ushort4 uq = *(const ushort4*)(qkv + base + m * 3072);
    ushort4 uk = *(const ushort4*)(qkv + base + m * 3072 + 1024);
    ushort4 uv = *(const ushort4*)(qkv + base + m * 3072 + 2048);
    q[m][0] = bf2f(uq.x); q[m][1] = bf2f(uq.y); q[m][2] = bf2f(uq.z); q[m][3] = bf2f(uq.w);
    k[m][0] = bf2f(uk.x); k[m][1] = bf2f(uk.y); k[m][2] = bf2f(uk.z); k[m][3] = bf2f(uk.w);
    v[m][0] = bf2f(uv.x); v[m][1] = bf2f(uv.y); v[m][2] = bf2f(uv.z); v[m][3] = bf2f(uv.w);
  }

  float s[16];
#pragma unroll
  for (int i = 0; i < 4; ++i)
#pragma unroll
    for (int j = 0; j < 4; ++j) {
      float acc = q[i][0] * k[j][0];
      acc += q[i][1] * k[j][1];
      acc += q[i][2] * k[j][2];
      acc += q[i][3] * k[j][3];
      s[i * 4 + j] = acc;
    }
#pragma unroll
  for (int off = 1; off < 16; off <<= 1) {
#pragma unroll
    for (int t = 0; t < 16; ++t) s[t] += __shfl_xor(s[t], off);
  }

  float a[16];
#pragma unroll
  for (int i = 0; i < 4; ++i) {
    float s0 = s[i * 4 + 0] * 0.125f, s1 = s[i * 4 + 1] * 0.125f;
    float s2 = s[i * 4 + 2] * 0.125f, s3 = s[i * 4 + 3] * 0.125f;
    float m = fmaxf(fmaxf(s0, s1), fmaxf(s2, s3));
    float e0 = __expf(s0 - m), e1 = __expf(s1 - m);
    float e2 = __expf(s2 - m), e3 = __expf(s3 - m);
    float inv = 1.0f / (e0 + e1 + e2 + e3);
    a[i * 4 + 0] = e0 * inv; a[i * 4 + 1] = e1 * inv;
    a[i * 4 + 2] = e2 * inv; a[i * 4 + 3] = e3 * inv;
  }

#pragma unroll
  for (int i = 0; i < 4; ++i) {
    float c0 = a[i*4+0]*v[0][0] + a[i*4+1]*v[1][0] + a[i*4+2]*v[2][0] + a[i*4+3]*v[3][0];
    float c1 = a[i*4+0]*v[0][1] + a[i*4+1]*v[1][1] + a[i*4+2]*v[2][1] + a[i*4+3]*v[3][1];
    float c2 = a[i*4+0]*v[0][2] + a[i*4+1]*v[1][2] + a[i*4+2]*v[2][2] + a[i*4+3]*v[3][2];
    float c3 = a[i*4+0]*v[0][3] + a[i*4+1]*v[1][3] + a[i*4+2]*v[2][3] + a[i*4+3]*v[3][3];
    ushort4 o;
    o.x = f2bf(c0); o.y = f2bf(c1); o.z = f2bf(c2); o.w = f2bf(c3);
    *(ushort4*)(ctxb + (size_t)b * 4096 + i * 1024 + h0 * 64 + l * 4) = o;
  }

  int sel = l & 15;
  float val = a[0];
#pragma unroll
  for (int t = 1; t < 16; ++t) val = (sel == t) ? a[t] : val;
  attn_out[(size_t)b * 256 + h0 * 16 + l] = val;
}

// --------------------------- layernorm -------------------------------------
__global__ __launch_bounds__(256) void ln_k(const float* __restrict__ pre,
                                            const float* __restrict__ g,
                                            const float* __restrict__ b,
                                            float* __restrict__ out) {
  int row = blockIdx.x;
  int tid = threadIdx.x;
  const float4 x = *(const float4*)(pre + (size_t)row * 1024 + tid * 4);
  float s = x.x + x.y + x.z + x.w;
  float s2 = x.x * x.x + x.y * x.y + x.z * x.z + x.w * x.w;
#pragma unroll
  for (int off = 32; off; off >>= 1) {
    s += __shfl_xor(s, off);
    s2 += __shfl_xor(s2, off);
  }
  __shared__ float r1[4], r2[4];
  int w = tid >> 6, lane = tid & 63;
  if (lane == 0) { r1[w] = s; r2[w] = s2; }
  __syncthreads();
  s = r1[0] + r1[1] + r1[2] + r1[3];
  s2 = r2[0] + r2[1] + r2[2] + r2[3];
  float mu = s * (1.0f / 1024.0f);
  float inv = rsqrtf(s2 * (1.0f / 1024.0f) - mu * mu + 1e-6f);
  float4 gv = *(const float4*)(g + tid * 4);
  float4 bv = *(const float4*)(b + tid * 4);
  float4 o;
  o.x = (x.x - mu) * inv * gv.x + bv.x;
  o.y = (x.y - mu) * inv * gv.y + bv.y;
  o.z = (x.z - mu) * inv * gv.z + bv.z;
  o.w = (x.w - mu) * inv * gv.w + bv.w;
  *(float4*)(out + (size_t)row * 1024 + tid * 4) = o;
}

// ---------------------------------------------------------------------------
extern "C" void kernel_launch(void* const* d_in, const int* in_sizes, int n_in,
                              void* d_out, int out_size, void* d_ws,
                              size_t ws_size, hipStream_t stream) {
  const float* fcb = (const float*)d_in[14];
  const float* lng = (const float*)d_in[15];
  const float* lnb = (const float*)d_in[16];

  u16* wsb = (u16*)d_ws;
  u16* xb = wsb;                 // 62,914,560
  u16* wb = xb + 62914560;       // 24,641,536
  u16* qkv = wb + 24641536;      // 100,663,296  [b][mod][q|k|v][1024]
  u16* ctxb = qkv + 100663296;   // 33,554,432
  float* pre = (float*)d_ws;     // 134MB overlays xb+wb head (fc_w @173MB safe)
  float* outp = (float*)d_out;
  float* attn_out = outp + 33554432;

  static const unsigned long woff[13] = {
      0,        2097152,  4194304,   // mod0 K=2048 (q,k,v)
      6291456,  7340032,  8388608,   // mod1 K=1024
      9437184,  9961472,  10485760,  // mod2 K=512
      11010048, 15204352, 19398656,  // mod3 K=4096
      23592960};                     // fc
  static const int wn4[13] = {524288, 524288, 524288, 262144, 262144, 262144,
                              131072, 131072, 131072, 1048576, 1048576, 1048576,
                              262144};

  // K1: one conversion dispatch
  CArgs ca;
  ca.src[0] = (const float*)d_in[0];
  ca.dst[0] = 0;
  ca.n4[0] = 62914560 / 4;
  ca.blk0[0] = 0;
  int nb = ca.n4[0] / 256;
  for (int i = 0; i < 13; ++i) {
    ca.src[i + 1] = (const float*)d_in[1 + i];
    ca.dst[i + 1] = 62914560ul + woff[i];
    ca.n4[i + 1] = wn4[i];
    ca.blk0[i + 1] = nb;
    nb += (wn4[i] + 255) / 256;
  }
  convall<<<dim3(nb), 256, 0, stream>>>(ca, wsb);

  // K2: grouped QKV projections, one dispatch (4 segs x 384 blocks, LPT)
  gemm8<0><<<dim3(1536), 512, 0, stream>>>(xb, 7680, wb, qkv, nullptr, nullptr,
                                           nullptr);

  // K3: attention
  attn_k<<<dim3(8192), 256, 0, stream>>>(qkv, ctxb, attn_out);

  // K4: FC + bias + residual -> pre-LN f32
  gemm8<1><<<dim3(512), 512, 0, stream>>>(ctxb, 1024, wb + 23592960, nullptr,
                                          pre, fcb, qkv);

  // K5: LayerNorm -> out
  ln_k<<<dim3(32768), 256, 0, stream>>>(pre, lng, lnb, outp);
}